// Round 11
// baseline (355.169 us; speedup 1.0000x reference)
//
#include <hip/hip_runtime.h>
#include <hip/hip_bf16.h>
#include <math.h>

// Problem constants
#define BB 4
#define LL 1024
#define DD 1024
#define HH 16
#define DHH 64
#define FFF 4096
#define MM (BB*LL)     // 4096 rows
#define LDQ 3072       // fused QKV row stride

typedef __attribute__((ext_vector_type(8))) short short8;
typedef __attribute__((ext_vector_type(4))) float f32x4;

__device__ __forceinline__ ushort f2bf(float f) {
    __hip_bfloat16 h = __float2bfloat16(f);
    return *(ushort*)&h;
}
__device__ __forceinline__ float bf2f(ushort u) {
    __hip_bfloat16 h = *(__hip_bfloat16*)&u;
    return __bfloat162float(h);
}
__device__ __forceinline__ float fexp2(float x) {
#if __has_builtin(__builtin_amdgcn_exp2f)
    return __builtin_amdgcn_exp2f(x);
#else
    return exp2f(x);
#endif
}

// ======= fused setup: cast x | bias pre-swizzle | concat3 | 5 transposes ===
// flat grid 16396:
//   [0,4096)      cast rows of x -> xb (bf16)
//   [4096,8192)   attn_bias rows -> biasw (fp32, log2e folded, swizzled)
//   [8192,8204)   concat bq|bk|bv -> bqkv
//   [8204,12300)  four 1024x1024 weight transposes (wq,wk,wv -> WQKVT; wo -> WOT)
//   [12300,16396) w1 1024x4096 transpose -> W1T
__global__ __launch_bounds__(256)
void setup_fused(const float* __restrict__ x, ushort* __restrict__ xb,
                 const float* __restrict__ bias, float* __restrict__ biasw,
                 const float* __restrict__ bq, const float* __restrict__ bk,
                 const float* __restrict__ bv, float* __restrict__ bqkv,
                 const float* __restrict__ wq, const float* __restrict__ wk,
                 const float* __restrict__ wv, const float* __restrict__ wo,
                 const float* __restrict__ w1,
                 ushort* __restrict__ WQKVT, ushort* __restrict__ WOT,
                 ushort* __restrict__ W1T) {
    __shared__ float smem[1056];               // max(rowbuf 1024, tile 32x33)
    const int id = blockIdx.x;
    const int t = threadIdx.x;
    if (id < 4096) {
        const int i = id * 256 + t;
        float4 v = ((const float4*)x)[i];
        ushort4 o;
        o.x = f2bf(v.x); o.y = f2bf(v.y); o.z = f2bf(v.z); o.w = f2bf(v.w);
        ((ushort4*)xb)[i] = o;
    } else if (id < 8192) {
        float* rowbuf = smem;
        const int row = id - 4096;
        *(float4*)&rowbuf[t * 4] = *(const float4*)&bias[(size_t)row * 1024 + t * 4];
        __syncthreads();
        const int kt = t >> 4, c = t & 15;
        const float s = 1.4426950408889634f;
        float4 o;
        o.x = rowbuf[kt * 64 + 0 * 16 + c] * s;
        o.y = rowbuf[kt * 64 + 1 * 16 + c] * s;
        o.z = rowbuf[kt * 64 + 2 * 16 + c] * s;
        o.w = rowbuf[kt * 64 + 3 * 16 + c] * s;
        *(float4*)&biasw[(size_t)row * 1024 + t * 4] = o;
    } else if (id < 8204) {
        const int i = (id - 8192) * 256 + t;
        bqkv[i] = (i < 1024) ? bq[i] : ((i < 2048) ? bk[i - 1024] : bv[i - 2048]);
    } else {
        float (*tile)[33] = (float(*)[33])smem;
        const int wid = id - 8204;
        const float* W;
        ushort* WT;
        int N, n0, k0;
        const int K = 1024;
        if (wid < 4096) {
            const int which = wid >> 10, b = wid & 1023;
            n0 = (b & 31) * 32; k0 = (b >> 5) * 32;
            N = 1024;
            W  = (which == 0) ? wq : (which == 1) ? wk : (which == 2) ? wv : wo;
            WT = (which < 3) ? (WQKVT + (size_t)which * 1024 * 1024) : WOT;
        } else {
            const int b = wid - 4096;
            n0 = (b & 127) * 32; k0 = (b >> 7) * 32;
            N = 4096;
            W = w1; WT = W1T;
        }
        const int r = t >> 3, c4 = (t & 7) * 4;
        float4 v = *(const float4*)&W[(size_t)(k0 + r) * N + n0 + c4];
        tile[r][c4 + 0] = v.x; tile[r][c4 + 1] = v.y;
        tile[r][c4 + 2] = v.z; tile[r][c4 + 3] = v.w;
        __syncthreads();
        ushort4 o;
        o.x = f2bf(tile[c4 + 0][r]);
        o.y = f2bf(tile[c4 + 1][r]);
        o.z = f2bf(tile[c4 + 2][r]);
        o.w = f2bf(tile[c4 + 3][r]);
        *(ushort4*)&WT[(size_t)(n0 + r) * K + k0 + c4] = o;
    }
}

// ---------------- tiled transpose + cast: W[K][N] fp32 -> WT[N][K] bf16 ----
// (still used for w2, which can only be transposed after FFN1 frees its dest)
__global__ __launch_bounds__(256)
void transpose_cast(const float* __restrict__ W, ushort* __restrict__ WT,
                    int K, int N) {
    __shared__ float tile[32][33];
    const int n0 = blockIdx.x * 32, k0 = blockIdx.y * 32;
    const int t = threadIdx.x;
    const int r = t >> 3, c4 = (t & 7) * 4;
    float4 v = *(const float4*)&W[(size_t)(k0 + r) * N + n0 + c4];
    tile[r][c4 + 0] = v.x; tile[r][c4 + 1] = v.y;
    tile[r][c4 + 2] = v.z; tile[r][c4 + 3] = v.w;
    __syncthreads();
    ushort4 o;
    o.x = f2bf(tile[c4 + 0][r]);
    o.y = f2bf(tile[c4 + 1][r]);
    o.z = f2bf(tile[c4 + 2][r]);
    o.w = f2bf(tile[c4 + 3][r]);
    *(ushort4*)&WT[(size_t)(n0 + r) * K + k0 + c4] = o;
}

// ---------------- bf16 MFMA GEMM, BK=64 (twin buffers) + XCD swizzle ------
// Full-K version (QKV). Measured-best for the M=4096,N=3072,K=1024 shape
// (768 blocks = 3/CU; 256-thread 128-wide tile). Epilogue: j-outer form
// (j-inner reorder raised VGPR 80->96 and cost occupancy; reverted r9).
template<int BN>
__global__ __launch_bounds__(256)
void gemm_bf16(const ushort* __restrict__ A, const ushort* __restrict__ Bt,
               const float* __restrict__ bias, void* __restrict__ C,
               ushort* __restrict__ Vt, int vn0,
               int M, int N, int K, int relu, int obf16, int qlim) {
    constexpr int JF = BN / 32;
    __shared__ ushort Als0[128 * 32];
    __shared__ ushort Als1[128 * 32];
    __shared__ ushort Bls0[BN * 32];
    __shared__ ushort Bls1[BN * 32];

    const int L = blockIdx.x + gridDim.x * blockIdx.y;
    const int xcd = L & 7;
    const int idx = L >> 3;
    const int mpx = gridDim.y >> 3;
    const int bm = (xcd * mpx + (idx % mpx)) * 128;
    const int bn = (idx / mpx) * BN;

    const int t = threadIdx.x;
    const int lane = t & 63;
    const int w = t >> 6;
    const int wm = (w >> 1) * 64;
    const int wn = (w & 1) * (BN / 2);
    const int fm = lane & 15;
    const int kg = lane >> 4;

    f32x4 acc[4][JF] = {};

    for (int k0 = 0; k0 < K; k0 += 64) {
        #pragma unroll
        for (int j = 0; j < 2; ++j) {
            const int chunk = j * 256 + t;
            const int row = chunk >> 2, kc = chunk & 3;
            const ushort* ga0 = A + (size_t)(bm + row) * K + k0 + kc * 8;
            __builtin_amdgcn_global_load_lds(
                (const __attribute__((address_space(1))) void*)ga0,
                (__attribute__((address_space(3))) void*)(Als0 + chunk * 8), 16, 0, 0);
            const ushort* ga1 = ga0 + 32;
            __builtin_amdgcn_global_load_lds(
                (const __attribute__((address_space(1))) void*)ga1,
                (__attribute__((address_space(3))) void*)(Als1 + chunk * 8), 16, 0, 0);
        }
        #pragma unroll
        for (int j = 0; j < BN / 64; ++j) {
            const int chunk = j * 256 + t;
            const int row = chunk >> 2, kc = chunk & 3;
            const ushort* gb0 = Bt + (size_t)(bn + row) * K + k0 + kc * 8;
            __builtin_amdgcn_global_load_lds(
                (const __attribute__((address_space(1))) void*)gb0,
                (__attribute__((address_space(3))) void*)(Bls0 + chunk * 8), 16, 0, 0);
            const ushort* gb1 = gb0 + 32;
            __builtin_amdgcn_global_load_lds(
                (const __attribute__((address_space(1))) void*)gb1,
                (__attribute__((address_space(3))) void*)(Bls1 + chunk * 8), 16, 0, 0);
        }
        __syncthreads();

        short8 af[4][2], bfr[JF][2];
        #pragma unroll
        for (int i = 0; i < 4; ++i) {
            af[i][0] = *(const short8*)&Als0[(wm + i * 16 + fm) * 32 + kg * 8];
            af[i][1] = *(const short8*)&Als1[(wm + i * 16 + fm) * 32 + kg * 8];
        }
        #pragma unroll
        for (int j = 0; j < JF; ++j) {
            bfr[j][0] = *(const short8*)&Bls0[(wn + j * 16 + fm) * 32 + kg * 8];
            bfr[j][1] = *(const short8*)&Bls1[(wn + j * 16 + fm) * 32 + kg * 8];
        }
        #pragma unroll
        for (int i = 0; i < 4; ++i)
            #pragma unroll
            for (int j = 0; j < JF; ++j) {
                acc[i][j] = __builtin_amdgcn_mfma_f32_16x16x32_bf16(
                    af[i][0], bfr[j][0], acc[i][j], 0, 0, 0);
                acc[i][j] = __builtin_amdgcn_mfma_f32_16x16x32_bf16(
                    af[i][1], bfr[j][1], acc[i][j], 0, 0, 0);
            }
        __syncthreads();
    }

    const int orow0 = (lane >> 4) * 4;
    const int ocol = lane & 15;
    #pragma unroll
    for (int j = 0; j < JF; ++j) {
        const int n = bn + wn + j * 16 + ocol;
        const float bv = bias[n];
        const bool isV = (bn + wn + j * 16) >= vn0;
        #pragma unroll
        for (int i = 0; i < 4; ++i) {
            const int m0 = bm + wm + i * 16 + orow0;
            if (isV) {
                ushort4 o;
                float v0 = acc[i][j][0] + bv, v1 = acc[i][j][1] + bv;
                float v2 = acc[i][j][2] + bv, v3 = acc[i][j][3] + bv;
                o.x = f2bf(v0); o.y = f2bf(v1); o.z = f2bf(v2); o.w = f2bf(v3);
                *(ushort4*)&Vt[((size_t)((m0 >> 10) << 10) + (n - vn0)) * 1024 + (m0 & 1023)] = o;
            } else {
                #pragma unroll
                for (int r = 0; r < 4; ++r) {
                    const int m = m0 + r;
                    float v = acc[i][j][r] + bv;
                    if (relu) v = fmaxf(v, 0.0f);
                    if (n < qlim) v *= 0.125f;
                    if (obf16)
                        ((ushort*)C)[(size_t)m * N + n] = f2bf(v);
                    else
                        ((float*)C)[(size_t)m * N + n] = v;
                }
            }
        }
    }
}

// ---------------- split-K bf16 MFMA GEMM, fp32 partials --------------------
// Mixed deployment (r11, both measured): WO uses BN=128 (K=512/block —
// prologue-dominated regime where the bigger tile won, r10 total-delta);
// FFN2 uses BN=64 (K=2048/block — BN=128's occupancy drop 32->17.8% made
// it 53.4us vs 50.3us, reverted per r10 decision rule).
template<int BN>
__global__ __launch_bounds__(256)
void gemm_bf16_sk(const ushort* __restrict__ A, const ushort* __restrict__ Bt,
                  float* __restrict__ P, int M, int N, int K) {
    constexpr int JF = BN / 32;
    __shared__ ushort Als0[128 * 32];
    __shared__ ushort Als1[128 * 32];
    __shared__ ushort Bls0[BN * 32];
    __shared__ ushort Bls1[BN * 32];

    const int L = blockIdx.x + gridDim.x * blockIdx.y;
    const int xcd = L & 7;
    const int idx = L >> 3;
    const int mpx = gridDim.y >> 3;
    const int bm = (xcd * mpx + (idx % mpx)) * 128;
    const int bn = (idx / mpx) * BN;
    const int kbeg = blockIdx.z * (K >> 1);
    const int kend = kbeg + (K >> 1);

    const int t = threadIdx.x;
    const int lane = t & 63;
    const int w = t >> 6;
    const int wm = (w >> 1) * 64;
    const int wn = (w & 1) * (BN / 2);
    const int fm = lane & 15;
    const int kg = lane >> 4;

    f32x4 acc[4][JF] = {};

    for (int k0 = kbeg; k0 < kend; k0 += 64) {
        #pragma unroll
        for (int j = 0; j < 2; ++j) {
            const int chunk = j * 256 + t;
            const int row = chunk >> 2, kc = chunk & 3;
            const ushort* ga0 = A + (size_t)(bm + row) * K + k0 + kc * 8;
            __builtin_amdgcn_global_load_lds(
                (const __attribute__((address_space(1))) void*)ga0,
                (__attribute__((address_space(3))) void*)(Als0 + chunk * 8), 16, 0, 0);
            const ushort* ga1 = ga0 + 32;
            __builtin_amdgcn_global_load_lds(
                (const __attribute__((address_space(1))) void*)ga1,
                (__attribute__((address_space(3))) void*)(Als1 + chunk * 8), 16, 0, 0);
        }
        #pragma unroll
        for (int j = 0; j < BN / 64; ++j) {
            const int chunk = j * 256 + t;
            const int row = chunk >> 2, kc = chunk & 3;
            const ushort* gb0 = Bt + (size_t)(bn + row) * K + k0 + kc * 8;
            __builtin_amdgcn_global_load_lds(
                (const __attribute__((address_space(1))) void*)gb0,
                (__attribute__((address_space(3))) void*)(Bls0 + chunk * 8), 16, 0, 0);
            const ushort* gb1 = gb0 + 32;
            __builtin_amdgcn_global_load_lds(
                (const __attribute__((address_space(1))) void*)gb1,
                (__attribute__((address_space(3))) void*)(Bls1 + chunk * 8), 16, 0, 0);
        }
        __syncthreads();

        short8 af[4][2], bfr[JF][2];
        #pragma unroll
        for (int i = 0; i < 4; ++i) {
            af[i][0] = *(const short8*)&Als0[(wm + i * 16 + fm) * 32 + kg * 8];
            af[i][1] = *(const short8*)&Als1[(wm + i * 16 + fm) * 32 + kg * 8];
        }
        #pragma unroll
        for (int j = 0; j < JF; ++j) {
            bfr[j][0] = *(const short8*)&Bls0[(wn + j * 16 + fm) * 32 + kg * 8];
            bfr[j][1] = *(const short8*)&Bls1[(wn + j * 16 + fm) * 32 + kg * 8];
        }
        #pragma unroll
        for (int i = 0; i < 4; ++i)
            #pragma unroll
            for (int j = 0; j < JF; ++j) {
                acc[i][j] = __builtin_amdgcn_mfma_f32_16x16x32_bf16(
                    af[i][0], bfr[j][0], acc[i][j], 0, 0, 0);
                acc[i][j] = __builtin_amdgcn_mfma_f32_16x16x32_bf16(
                    af[i][1], bfr[j][1], acc[i][j], 0, 0, 0);
            }
        __syncthreads();
    }

    float* Pz = P + (size_t)blockIdx.z * M * N;
    const int orow0 = (lane >> 4) * 4;
    const int ocol = lane & 15;
    #pragma unroll
    for (int j = 0; j < JF; ++j) {
        const int n = bn + wn + j * 16 + ocol;
        #pragma unroll
        for (int i = 0; i < 4; ++i) {
            const int m0 = bm + wm + i * 16 + orow0;
            #pragma unroll
            for (int r = 0; r < 4; ++r)
                Pz[(size_t)(m0 + r) * N + n] = acc[i][j][r];
        }
    }
}

// ================= shared pieces for the 8-phase GEMM ======================
// Swizzle: 16B slot index (3 bits, byte-col bits 4-6) XORed with (row&7)
// within each [128 rows][64 bf16] half -> conflict-free ds_read_b128
// (verified: SQ_LDS_BANK_CONFLICT == 0 on HW). Applied both-sides (rule 21):
// linear global_load_lds dest + inverse-swizzled GLOBAL source column +
// same XOR on the ds_read address.

#define BARM() asm volatile("s_barrier" ::: "memory")
#define VMC4() asm volatile("s_waitcnt vmcnt(4)" ::: "memory")
#define LGK0() do { asm volatile("s_waitcnt lgkmcnt(0)" ::: "memory"); \
                    __builtin_amdgcn_sched_barrier(0); } while (0)

__device__ __forceinline__ short8 fragrd(const ushort* h, int row, int s, int kg) {
    const int cb = ((s << 6) + (kg << 4)) ^ ((row & 7) << 4);
    return *(const short8*)(h + row * 64 + (cb >> 1));
}

__device__ __forceinline__ void stage_half(const ushort* __restrict__ src,
                                           int srcK, ushort* ldsh, int t) {
    // src points to element (row0, kcol0) of a 128x64 half; row stride = srcK.
    #pragma unroll
    for (int l = 0; l < 2; ++l) {
        const int chunk = l * 512 + t;          // 0..1023, 16B each
        const int r = chunk >> 3;
        const int cb_log = ((chunk & 7) * 16) ^ ((r & 7) << 4);
        const ushort* g = src + (size_t)r * srcK + (cb_log >> 1);
        __builtin_amdgcn_global_load_lds(
            (const __attribute__((address_space(1))) void*)g,
            (__attribute__((address_space(3))) void*)(ldsh + chunk * 8), 16, 0, 0);
    }
}

// =================== 256x256 8-phase GEMM (T2+T3+T4+T5) ====================
// BM=BN=256, BK=64, 512 threads = 8 waves (2M x 4N), per-wave out 128x64.
// Counted vmcnt(4) at phases 4 and 8 only; never vmcnt(0) in the main loop.
// Epilogue: row-segment stores (nj innermost) — both 64B lines of each row
// segment complete back-to-back (fixes 2.5x write amplification).
// Requires: M == 4096, N%256==0, K%128==0, grid = 16*(N/256), grid%8==0.
__global__ __launch_bounds__(512, 2)
void gemm256(const ushort* __restrict__ A, const ushort* __restrict__ Bt,
             const float* __restrict__ bias, ushort* __restrict__ C,
             int M, int N, int K, int relu, int qlim) {
    __shared__ ushort lds[65536];              // 128 KiB

    const int nt = K >> 6;                     // BK=64 tiles (even)
    const int t = threadIdx.x;
    const int lane = t & 63;
    const int w = t >> 6;
    const int wr = w >> 2, wc = w & 3;
    const int fm = lane & 15, kg = lane >> 4;

    const int bid = blockIdx.x;
    const int wg = (bid & 7) * (gridDim.x >> 3) + (bid >> 3);
    const int bm = (wg & 15) << 8;
    const int bn = (wg >> 4) << 8;

    ushort* const A0 = lds;
    ushort* const B0 = lds + 16384;
    ushort* const A1 = lds + 32768;
    ushort* const B1 = lds + 49152;

    const ushort* const Ah0 = A0 + wr * 8192;
    const ushort* const Ah1 = A1 + wr * 8192;
    const ushort* const Bh0 = B0 + (wc >> 1) * 8192;
    const ushort* const Bh1 = B1 + (wc >> 1) * 8192;
    const int brow = (wc & 1) * 64;

    #define ASRC(tt, h) (A  + (size_t)(bm + (h) * 128) * K + (tt) * 64)
    #define BSRC(tt, h) (Bt + (size_t)(bn + (h) * 128) * K + (tt) * 64)

    f32x4 acc[8][4] = {};
    short8 af[4][2];
    short8 bf2[4][2];

    #define RD_A(HP, MI0) do { \
        _Pragma("unroll") \
        for (int i = 0; i < 4; ++i) { \
            const int row = ((MI0) + i) * 16 + fm; \
            af[i][0] = fragrd((HP), row, 0, kg); \
            af[i][1] = fragrd((HP), row, 1, kg); \
        } } while (0)

    #define RD_B(HP, J0) do { \
        _Pragma("unroll") \
        for (int jj = 0; jj < 2; ++jj) { \
            const int row = brow + ((J0) + jj) * 16 + fm; \
            bf2[(J0) + jj][0] = fragrd((HP), row, 0, kg); \
            bf2[(J0) + jj][1] = fragrd((HP), row, 1, kg); \
        } } while (0)

    #define QMFMA(MI0, J0) do { \
        __builtin_amdgcn_s_setprio(1); \
        _Pragma("unroll") \
        for (int i = 0; i < 4; ++i) { \
            _Pragma("unroll") \
            for (int jj = 0; jj < 2; ++jj) { \
                acc[(MI0)+i][(J0)+jj] = __builtin_amdgcn_mfma_f32_16x16x32_bf16( \
                    af[i][0], bf2[(J0)+jj][0], acc[(MI0)+i][(J0)+jj], 0, 0, 0); \
                acc[(MI0)+i][(J0)+jj] = __builtin_amdgcn_mfma_f32_16x16x32_bf16( \
                    af[i][1], bf2[(J0)+jj][1], acc[(MI0)+i][(J0)+jj], 0, 0, 0); \
            } } \
        __builtin_amdgcn_s_setprio(0); \
    } while (0)

    stage_half(BSRC(0, 0), K, B0, t);
    stage_half(BSRC(0, 1), K, B0 + 8192, t);
    stage_half(ASRC(0, 0), K, A0, t);
    stage_half(ASRC(0, 1), K, A0 + 8192, t);
    stage_half(BSRC(1, 0), K, B1, t);
    stage_half(BSRC(1, 1), K, B1 + 8192, t);
    VMC4();
    BARM();

    for (int it = 0; it < (nt >> 1); ++it) {
        const int ta = 2 * it;
        const int tb = ta + 1;
        const int t2 = min(ta + 2, nt - 1);
        const int t3 = min(ta + 3, nt - 1);

        RD_A(Ah0, 0); RD_B(Bh0, 0);
        stage_half(ASRC(tb, 0), K, A1, t);
        BARM(); LGK0(); QMFMA(0, 0); BARM();
        RD_B(Bh0, 2);
        stage_half(ASRC(tb, 1), K, A1 + 8192, t);
        BARM(); LGK0(); QMFMA(0, 2); BARM();
        RD_A(Ah0, 4);
        stage_half(BSRC(t2, 0), K, B0, t);
        BARM(); LGK0(); QMFMA(4, 2); BARM();
        stage_half(BSRC(t2, 1), K, B0 + 8192, t);
        VMC4();
        BARM(); LGK0(); QMFMA(4, 0); BARM();
        RD_A(Ah1, 0); RD_B(Bh1, 0);
        stage_half(ASRC(t2, 0), K, A0, t);
        BARM(); LGK0(); QMFMA(0, 0); BARM();
        RD_B(Bh1, 2);
        stage_half(ASRC(t2, 1), K, A0 + 8192, t);
        BARM(); LGK0(); QMFMA(0, 2); BARM();
        RD_A(Ah1, 4);
        stage_half(BSRC(t3, 0), K, B1, t);
        BARM(); LGK0(); QMFMA(4, 2); BARM();
        stage_half(BSRC(t3, 1), K, B1 + 8192, t);
        VMC4();
        BARM(); LGK0(); QMFMA(4, 0); BARM();
    }

    const int oc = lane & 15, og = lane >> 4;
    float bvv[4];
    #pragma unroll
    for (int nj = 0; nj < 4; ++nj)
        bvv[nj] = bias[bn + wc * 64 + nj * 16 + oc];
    #pragma unroll
    for (int mi = 0; mi < 8; ++mi) {
        const int m0 = bm + wr * 128 + mi * 16 + og * 4;
        #pragma unroll
        for (int r = 0; r < 4; ++r) {
            const size_t rowbase = (size_t)(m0 + r) * N;
            #pragma unroll
            for (int nj = 0; nj < 4; ++nj) {
                const int n = bn + wc * 64 + nj * 16 + oc;
                float v = acc[mi][nj][r] + bvv[nj];
                if (relu) v = fmaxf(v, 0.0f);
                if (n < qlim) v *= 0.125f;
                C[rowbase + n] = f2bf(v);
            }
        }
    }
    #undef ASRC
    #undef BSRC
    #undef RD_A
    #undef RD_B
    #undef QMFMA
}

// ---------------- MFMA flash attention, max-free softmax ----------------
__global__ __launch_bounds__(256, 4)
void attn_mfma(const ushort* __restrict__ QKVb, const ushort* __restrict__ Vt,
               const float* __restrict__ biasw, const int* __restrict__ mask,
               ushort* __restrict__ ctx) {
    const int q0 = blockIdx.x * 64;
    const int h = blockIdx.y;
    const int b = blockIdx.z;
    const int t = threadIdx.x;
    const int lane = t & 63;
    const int w = t >> 6;
    const int g = lane >> 4;
    const int c = lane & 15;

    __shared__ ushort QP[64 * 72];
    __shared__ ushort Ks[64 * 72];
    __shared__ ushort Vs[64 * 72];
    __shared__ float maskS[LL];

    #pragma unroll
    for (int i = 0; i < 2; ++i) {
        const int chunk = i * 256 + t;
        const int row = chunk >> 3, c8 = (chunk & 7) * 8;
        *(short8*)&QP[row * 72 + c8] =
            *(const short8*)(QKVb + ((size_t)(b * LL + q0 + row)) * LDQ + h * DHH + c8);
    }
    {
        int4 mi = ((const int4*)(mask + b * LL))[t];
        float4 mf;
        mf.x = mi.x ? 0.0f : -49152.0f;
        mf.y = mi.y ? 0.0f : -49152.0f;
        mf.z = mi.z ? 0.0f : -49152.0f;
        mf.w = mi.w ? 0.0f : -49152.0f;
        ((float4*)maskS)[t] = mf;
    }

    short8 pk[2], pv[2];
    #pragma unroll
    for (int i = 0; i < 2; ++i) {
        const int chunk = i * 256 + t;
        const int row = chunk >> 3, c8 = (chunk & 7) * 8;
        pk[i] = *(const short8*)(QKVb + ((size_t)(b * LL + row)) * LDQ + 1024 + h * DHH + c8);
        pv[i] = *(const short8*)(Vt + ((size_t)((b * HH + h) * DHH + row)) * LL + c8);
    }
    __syncthreads();

    short8 aq0 = *(const short8*)&QP[(w * 16 + c) * 72 + g * 8];
    short8 aq1 = *(const short8*)&QP[(w * 16 + c) * 72 + g * 8 + 32];
    ushort* Pw = QP + w * (16 * 72);

    const float* bp = biasw + (size_t)(b * LL + q0 + w * 16 + 4 * g) * 1024 + c * 4;
    float4 pb[4];
    #pragma unroll
    for (int r = 0; r < 4; ++r)
        pb[r] = *(const float4*)(bp + r * 1024);

    float l_run[4] = {0.f, 0.f, 0.f, 0.f};
    f32x4 acc_o[4] = {};

    for (int kt = 0; kt < 16; ++kt) {
        #pragma unroll
        for (int i = 0; i < 2; ++i) {
            const int chunk = i * 256 + t;
            const int row = chunk >> 3, c8 = (chunk & 7) * 8;
            *(short8*)&Ks[row * 72 + c8] = pk[i];
            *(short8*)&Vs[row * 72 + c8] = pv[i];
        }
        __syncthreads();

        if (kt < 15) {
            const int k0n = (kt + 1) * 64;
            #pragma unroll
            for (int i = 0; i < 2; ++i) {
                const int chunk = i * 256 + t;
                const int row = chunk >> 3, c8 = (chunk & 7) * 8;
                pk[i] = *(const short8*)(QKVb + ((size_t)(b * LL + k0n + row)) * LDQ + 1024 + h * DHH + c8);
                pv[i] = *(const short8*)(Vt + ((size_t)((b * HH + h) * DHH + row)) * LL + k0n + c8);
            }
        }

        float4 pbn[4];
        if (kt < 15) {
            #pragma unroll
            for (int r = 0; r < 4; ++r)
                pbn[r] = *(const float4*)(bp + r * 1024 + (kt + 1) * 64);
        }

        float mk[4];
        #pragma unroll
        for (int j = 0; j < 4; ++j) mk[j] = maskS[kt * 64 + j * 16 + c];

        f32x4 accs[4] = {};
        __builtin_amdgcn_s_setprio(1);
        #pragma unroll
        for (int j = 0; j < 4; ++j) {
            short8 bk0 = *(const short8*)&Ks[(j * 16 + c) * 72 + g * 8];
            short8 bk1 = *(const short8*)&Ks[(j * 16 + c) * 72 + g * 8 + 32];
            accs[j] = __builtin_amdgcn_mfma_f32_16x16x32_bf16(aq0, bk0, accs[j], 0, 0, 0);
            accs[j] = __builtin_amdgcn_mfma_f32_16x16x32_bf16(aq1, bk1, accs[j], 0, 0, 0);
        }
        __builtin_amdgcn_s_setprio(0);

        #pragma unroll
        for (int j = 0; j < 4; ++j)
            #pragma unroll
            for (int r = 0; r < 4; ++r) {
                const float pe = fexp2(fmaf(accs[j][r], ((const float*)&pb[r])[j], mk[j]));
                l_run[r] += pe;
                Pw[(4 * g + r) * 72 + j * 16 + c] = f2bf(pe);
            }

        __builtin_amdgcn_s_setprio(1);
        #pragma unroll
        for (int ks = 0; ks < 2; ++ks) {
            short8 ap = *(const short8*)&Pw[c * 72 + ks * 32 + g * 8];
            #pragma unroll
            for (int j = 0; j < 4; ++j) {
                short8 bv8 = *(const short8*)&Vs[(j * 16 + c) * 72 + ks * 32 + g * 8];
                acc_o[j] = __builtin_amdgcn_mfma_f32_16x16x32_bf16(ap, bv8, acc_o[j], 0, 0, 0);
            }
        }
        __builtin_amdgcn_s_setprio(0);

        if (kt < 15) {
            #pragma unroll
            for (int r = 0; r < 4; ++r) pb[r] = pbn[r];
        }
        __syncthreads();
    }

    #pragma unroll
    for (int r = 0; r < 4; ++r) {
        float l = l_run[r];
        #pragma unroll
        for (int d = 1; d < 16; d <<= 1) l += __shfl_xor(l, d);
        const float inv = 1.0f / l;
        #pragma unroll
        for (int j = 0; j < 4; ++j)
            ctx[((size_t)(b * LL + q0 + w * 16 + 4 * g + r)) * DD + h * DHH + j * 16 + c] =
                f2bf(acc_o[j][r] * inv);
    }
}

// ---------------- split-K reduce + col-bias + residual + LayerNorm ---------
// v = P0 + P1 + cb[col] + bres;  out = gamma*(v-mean)*rstd + beta  (+bf16)
// float4 everything; two-pass reduce via 64-lane shfl_xor + 4-slot LDS
// cross-wave combine (2 syncthreads total).
__global__ __launch_bounds__(256)
void add_ln_kernel(const float* __restrict__ P0, const float* __restrict__ P1,
                   const float* __restrict__ cb, const float* __restrict__ bres,
                   const float* __restrict__ gamma, const float* __restrict__ beta,
                   float* __restrict__ out, ushort* __restrict__ outb) {
    const int row = blockIdx.x;
    const int tid = threadIdx.x;
    const int lane = tid & 63;
    const int wv = tid >> 6;
    __shared__ float redS[8];

    const size_t base = (size_t)row * DD;
    const float4 p0 = ((const float4*)(P0 + base))[tid];
    const float4 p1 = ((const float4*)(P1 + base))[tid];
    const float4 br = ((const float4*)(bres + base))[tid];
    const float4 cv = ((const float4*)cb)[tid];
    float4 v;
    v.x = p0.x + p1.x + cv.x + br.x;
    v.y = p0.y + p1.y + cv.y + br.y;
    v.z = p0.z + p1.z + cv.z + br.z;
    v.w = p0.w + p1.w + cv.w + br.w;

    float s = v.x + v.y + v.z + v.w;
    #pragma unroll
    for (int d = 1; d < 64; d <<= 1) s += __shfl_xor(s, d);
    if (lane == 0) redS[wv] = s;
    __syncthreads();
    const float mean = (redS[0] + redS[1] + redS[2] + redS[3]) * (1.0f / 1024.0f);

    float4 dlt;
    dlt.x = v.x - mean; dlt.y = v.y - mean;
    dlt.z = v.z - mean; dlt.w = v.w - mean;
    float vs = dlt.x * dlt.x + dlt.y * dlt.y + dlt.z * dlt.z + dlt.w * dlt.w;
    #pragma unroll
    for (int d = 1; d < 64; d <<= 1) vs += __shfl_xor(vs, d);
    if (lane == 0) redS[4 + wv] = vs;
    __syncthreads();
    const float var = (redS[4] + redS[5] + redS[6] + redS[7]) * (1.0f / 1024.0f);
    const float rstd = rsqrtf(var + 1e-12f);

    const float4 g4 = ((const float4*)gamma)[tid];
    const float4 b4 = ((const float4*)beta)[tid];
    float4 o;
    o.x = g4.x * dlt.x * rstd + b4.x;
    o.y = g4.y * dlt.y * rstd + b4.y;
    o.z = g4.z * dlt.z * rstd + b4.z;
    o.w = g4.w * dlt.w * rstd + b4.w;
    if (out) ((float4*)(out + base))[tid] = o;
    if (outb) {
        ushort4 ob;
        ob.x = f2bf(o.x); ob.y = f2bf(o.y);
        ob.z = f2bf(o.z); ob.w = f2bf(o.w);
        ((ushort4*)(outb + base))[tid] = ob;
    }
}

extern "C" void kernel_launch(void* const* d_in, const int* in_sizes, int n_in,
                              void* d_out, int out_size, void* d_ws, size_t ws_size,
                              hipStream_t stream) {
    const float* x         = (const float*)d_in[0];
    const float* attn_bias = (const float*)d_in[1];
    const int*   src_mask  = (const int*)  d_in[2];
    const float* wq = (const float*)d_in[3];
    const float* bq = (const float*)d_in[4];
    const float* wk = (const float*)d_in[5];
    const float* bk = (const float*)d_in[6];
    const float* wv = (const float*)d_in[7];
    const float* bv = (const float*)d_in[8];
    const float* wo = (const float*)d_in[9];
    const float* bo = (const float*)d_in[10];
    const float* gamma1 = (const float*)d_in[11];
    const float* beta1  = (const float*)d_in[12];
    const float* w1 = (const float*)d_in[13];
    const float* b1 = (const float*)d_in[14];
    const float* w2 = (const float*)d_in[15];
    const float* b2 = (const float*)d_in[16];
    const float* gamma2 = (const float*)d_in[17];
    const float* beta2  = (const float*)d_in[18];
    float* out = (float*)d_out;

    // workspace arena (96 MB, time-multiplexed) — v6 layout:
    // [0,8):   xb -> ctxb (dead after WO)
    // [8,24):  QKVb(front) -> Hb fp32 (LN1 out, live till LN2)
    // [8,32):  QKVb full 24 MB (dead after attn)
    // [24,32): -> Hbb (LN1 out, FFN1 in) -> W2T (after FFN1)
    // [32,64): Vt[32,40) + WQKVT[40,46) + bqkv[46,~) + biasw[48,64)
    //          -> P_wo (WO out, LN1 in) -> F1b (FFN1 out, FFN2 in)
    // [64,72): W1T (written up-front; FFN1 in; dead)
    // [72,74): WOT (written up-front; WO in; dead)
    // [64,96): -> P_ffn2 (FFN2 out, LN2 in)
    const size_t MB = 1024 * 1024;
    char* W = (char*)d_ws;
    ushort* xb    = (ushort*)(W + 0);
    ushort* ctxb  = (ushort*)(W + 0);
    ushort* QKVb  = (ushort*)(W + 8 * MB);
    float*  Hb    = (float*) (W + 8 * MB);
    ushort* Hbb   = (ushort*)(W + 24 * MB);
    ushort* W2T   = (ushort*)(W + 24 * MB);
    ushort* Vt    = (ushort*)(W + 32 * MB);
    ushort* WQKVT = (ushort*)(W + 40 * MB);
    float*  bqkv  = (float*) (W + 46 * MB);
    float*  biasw = (float*) (W + 48 * MB);
    float*  Pwo   = (float*) (W + 32 * MB);   // 2 x 16 MB, after attn
    ushort* F1b   = (ushort*)(W + 32 * MB);   // 32 MB, after LN1
    ushort* W1T   = (ushort*)(W + 64 * MB);
    ushort* WOT   = (ushort*)(W + 72 * MB);
    float*  Pffn  = (float*) (W + 64 * MB);   // 2 x 16 MB, after FFN1

    dim3 blk(256);

    // 1. fused setup: x->xb, attn_bias->biasw, bias concat, 5 transposes
    setup_fused<<<dim3(16396), blk, 0, stream>>>(x, xb, attn_bias, biasw,
                                                 bq, bk, bv, bqkv,
                                                 wq, wk, wv, wo, w1,
                                                 WQKVT, WOT, W1T);
    // 2. fused QKV projection (bf16 out; Q scaled 0.125; V -> Vt transposed)
    gemm_bf16<128><<<dim3(24, 32), blk, 0, stream>>>(xb, WQKVT, bqkv, QKVb,
                                                     Vt, 2048, MM, LDQ, DD, 0, 1, 1024);
    // 3. MFMA flash attention -> ctx bf16
    attn_mfma<<<dim3(16, HH, BB), blk, 0, stream>>>(QKVb, Vt, biasw, src_mask, ctxb);
    // 4. split-K output projection (128x128 tiles; K=512/block — prologue-
    //    dominated regime where BN=128 measured faster). grid 8x32x2 = 512.
    gemm_bf16_sk<128><<<dim3(8, 32, 2), blk, 0, stream>>>(ctxb, WOT, Pwo, MM, DD, DD);
    // 5. h = LN(Pwo0+Pwo1+bo + x) -> Hb fp32 + Hbb bf16
    add_ln_kernel<<<dim3(MM), blk, 0, stream>>>(Pwo, Pwo + (size_t)MM * DD, bo, x,
                                                gamma1, beta1, Hb, Hbb);
    // 6. FFN1 via 256x256 8-phase kernel (relu, bias, bf16) -> F1b
    gemm256<<<dim3(256), dim3(512), 0, stream>>>(Hbb, W1T, b1, F1b,
                                                 MM, FFF, DD, 1, 0);
    // 7. W2 transpose into dead Hbb region
    transpose_cast<<<dim3(32, 128), blk, 0, stream>>>(w2, W2T, FFF, DD);
    // 8. split-K FFN2 (64-wide tiles; K=2048/block — occupancy-bound regime
    //    where BN=64's 4 blocks/CU measured faster: 50.3 vs 53.4us). 
    gemm_bf16_sk<64><<<dim3(16, 32, 2), blk, 0, stream>>>(F1b, W2T, Pffn, MM, DD, FFF);
    // 9. out = LN(Pffn0+Pffn1+b2 + h)
    add_ln_kernel<<<dim3(MM), blk, 0, stream>>>(Pffn, Pffn + (size_t)MM * DD, b2, Hb,
                                                gamma2, beta2, out, nullptr);
}

// Round 12
// 352.494 us; speedup vs baseline: 1.0076x; 1.0076x over previous
//
#include <hip/hip_runtime.h>
#include <hip/hip_bf16.h>
#include <math.h>

// Problem constants
#define BB 4
#define LL 1024
#define DD 1024
#define HH 16
#define DHH 64
#define FFF 4096
#define MM (BB*LL)     // 4096 rows
#define LDQ 3072       // fused QKV row stride

typedef __attribute__((ext_vector_type(8))) short short8;
typedef __attribute__((ext_vector_type(4))) float f32x4;

__device__ __forceinline__ ushort f2bf(float f) {
    __hip_bfloat16 h = __float2bfloat16(f);
    return *(ushort*)&h;
}
__device__ __forceinline__ float bf2f(ushort u) {
    __hip_bfloat16 h = *(__hip_bfloat16*)&u;
    return __bfloat162float(h);
}
__device__ __forceinline__ float fexp2(float x) {
#if __has_builtin(__builtin_amdgcn_exp2f)
    return __builtin_amdgcn_exp2f(x);
#else
    return exp2f(x);
#endif
}

// ======= fused setup: cast x | bias pre-swizzle | concat3 | 5 transposes ===
// flat grid 16396:
//   [0,4096)      cast rows of x -> xb (bf16)
//   [4096,8192)   attn_bias rows -> biasw (fp32, log2e folded, swizzled)
//   [8192,8204)   concat bq|bk|bv -> bqkv
//   [8204,12300)  four 1024x1024 weight transposes (wq,wk,wv -> WQKVT; wo -> WOT)
//   [12300,16396) w1 1024x4096 transpose -> W1T
__global__ __launch_bounds__(256)
void setup_fused(const float* __restrict__ x, ushort* __restrict__ xb,
                 const float* __restrict__ bias, float* __restrict__ biasw,
                 const float* __restrict__ bq, const float* __restrict__ bk,
                 const float* __restrict__ bv, float* __restrict__ bqkv,
                 const float* __restrict__ wq, const float* __restrict__ wk,
                 const float* __restrict__ wv, const float* __restrict__ wo,
                 const float* __restrict__ w1,
                 ushort* __restrict__ WQKVT, ushort* __restrict__ WOT,
                 ushort* __restrict__ W1T) {
    __shared__ float smem[1056];               // max(rowbuf 1024, tile 32x33)
    const int id = blockIdx.x;
    const int t = threadIdx.x;
    if (id < 4096) {
        const int i = id * 256 + t;
        float4 v = ((const float4*)x)[i];
        ushort4 o;
        o.x = f2bf(v.x); o.y = f2bf(v.y); o.z = f2bf(v.z); o.w = f2bf(v.w);
        ((ushort4*)xb)[i] = o;
    } else if (id < 8192) {
        float* rowbuf = smem;
        const int row = id - 4096;
        *(float4*)&rowbuf[t * 4] = *(const float4*)&bias[(size_t)row * 1024 + t * 4];
        __syncthreads();
        const int kt = t >> 4, c = t & 15;
        const float s = 1.4426950408889634f;
        float4 o;
        o.x = rowbuf[kt * 64 + 0 * 16 + c] * s;
        o.y = rowbuf[kt * 64 + 1 * 16 + c] * s;
        o.z = rowbuf[kt * 64 + 2 * 16 + c] * s;
        o.w = rowbuf[kt * 64 + 3 * 16 + c] * s;
        *(float4*)&biasw[(size_t)row * 1024 + t * 4] = o;
    } else if (id < 8204) {
        const int i = (id - 8192) * 256 + t;
        bqkv[i] = (i < 1024) ? bq[i] : ((i < 2048) ? bk[i - 1024] : bv[i - 2048]);
    } else {
        float (*tile)[33] = (float(*)[33])smem;
        const int wid = id - 8204;
        const float* W;
        ushort* WT;
        int N, n0, k0;
        const int K = 1024;
        if (wid < 4096) {
            const int which = wid >> 10, b = wid & 1023;
            n0 = (b & 31) * 32; k0 = (b >> 5) * 32;
            N = 1024;
            W  = (which == 0) ? wq : (which == 1) ? wk : (which == 2) ? wv : wo;
            WT = (which < 3) ? (WQKVT + (size_t)which * 1024 * 1024) : WOT;
        } else {
            const int b = wid - 4096;
            n0 = (b & 127) * 32; k0 = (b >> 7) * 32;
            N = 4096;
            W = w1; WT = W1T;
        }
        const int r = t >> 3, c4 = (t & 7) * 4;
        float4 v = *(const float4*)&W[(size_t)(k0 + r) * N + n0 + c4];
        tile[r][c4 + 0] = v.x; tile[r][c4 + 1] = v.y;
        tile[r][c4 + 2] = v.z; tile[r][c4 + 3] = v.w;
        __syncthreads();
        ushort4 o;
        o.x = f2bf(tile[c4 + 0][r]);
        o.y = f2bf(tile[c4 + 1][r]);
        o.z = f2bf(tile[c4 + 2][r]);
        o.w = f2bf(tile[c4 + 3][r]);
        *(ushort4*)&WT[(size_t)(n0 + r) * K + k0 + c4] = o;
    }
}

// ---------------- tiled transpose + cast: W[K][N] fp32 -> WT[N][K] bf16 ----
// (still used for w2, which can only be transposed after FFN1 frees its dest)
__global__ __launch_bounds__(256)
void transpose_cast(const float* __restrict__ W, ushort* __restrict__ WT,
                    int K, int N) {
    __shared__ float tile[32][33];
    const int n0 = blockIdx.x * 32, k0 = blockIdx.y * 32;
    const int t = threadIdx.x;
    const int r = t >> 3, c4 = (t & 7) * 4;
    float4 v = *(const float4*)&W[(size_t)(k0 + r) * N + n0 + c4];
    tile[r][c4 + 0] = v.x; tile[r][c4 + 1] = v.y;
    tile[r][c4 + 2] = v.z; tile[r][c4 + 3] = v.w;
    __syncthreads();
    ushort4 o;
    o.x = f2bf(tile[c4 + 0][r]);
    o.y = f2bf(tile[c4 + 1][r]);
    o.z = f2bf(tile[c4 + 2][r]);
    o.w = f2bf(tile[c4 + 3][r]);
    *(ushort4*)&WT[(size_t)(n0 + r) * K + k0 + c4] = o;
}

// ---------------- bf16 MFMA GEMM, BK=64 (twin buffers) + XCD swizzle ------
// Full-K version (QKV). Q/K epilogue: j processed in PAIRS so the two 32B
// half-lines of each 64B output line are stored in consecutive instructions
// (fixes 1.6x write amplification: WRITE_SIZE 39MB for 24MB output), while
// keeping the i/r loop order (full inversion raised VGPR 80->96, r8).
// V-transpose path unchanged (its lines already complete across adjacent
// i-stores). vn0/qlim are uniform at pair granularity (multiples of 32).
template<int BN>
__global__ __launch_bounds__(256)
void gemm_bf16(const ushort* __restrict__ A, const ushort* __restrict__ Bt,
               const float* __restrict__ bias, void* __restrict__ C,
               ushort* __restrict__ Vt, int vn0,
               int M, int N, int K, int relu, int obf16, int qlim) {
    constexpr int JF = BN / 32;
    __shared__ ushort Als0[128 * 32];
    __shared__ ushort Als1[128 * 32];
    __shared__ ushort Bls0[BN * 32];
    __shared__ ushort Bls1[BN * 32];

    const int L = blockIdx.x + gridDim.x * blockIdx.y;
    const int xcd = L & 7;
    const int idx = L >> 3;
    const int mpx = gridDim.y >> 3;
    const int bm = (xcd * mpx + (idx % mpx)) * 128;
    const int bn = (idx / mpx) * BN;

    const int t = threadIdx.x;
    const int lane = t & 63;
    const int w = t >> 6;
    const int wm = (w >> 1) * 64;
    const int wn = (w & 1) * (BN / 2);
    const int fm = lane & 15;
    const int kg = lane >> 4;

    f32x4 acc[4][JF] = {};

    for (int k0 = 0; k0 < K; k0 += 64) {
        #pragma unroll
        for (int j = 0; j < 2; ++j) {
            const int chunk = j * 256 + t;
            const int row = chunk >> 2, kc = chunk & 3;
            const ushort* ga0 = A + (size_t)(bm + row) * K + k0 + kc * 8;
            __builtin_amdgcn_global_load_lds(
                (const __attribute__((address_space(1))) void*)ga0,
                (__attribute__((address_space(3))) void*)(Als0 + chunk * 8), 16, 0, 0);
            const ushort* ga1 = ga0 + 32;
            __builtin_amdgcn_global_load_lds(
                (const __attribute__((address_space(1))) void*)ga1,
                (__attribute__((address_space(3))) void*)(Als1 + chunk * 8), 16, 0, 0);
        }
        #pragma unroll
        for (int j = 0; j < BN / 64; ++j) {
            const int chunk = j * 256 + t;
            const int row = chunk >> 2, kc = chunk & 3;
            const ushort* gb0 = Bt + (size_t)(bn + row) * K + k0 + kc * 8;
            __builtin_amdgcn_global_load_lds(
                (const __attribute__((address_space(1))) void*)gb0,
                (__attribute__((address_space(3))) void*)(Bls0 + chunk * 8), 16, 0, 0);
            const ushort* gb1 = gb0 + 32;
            __builtin_amdgcn_global_load_lds(
                (const __attribute__((address_space(1))) void*)gb1,
                (__attribute__((address_space(3))) void*)(Bls1 + chunk * 8), 16, 0, 0);
        }
        __syncthreads();

        short8 af[4][2], bfr[JF][2];
        #pragma unroll
        for (int i = 0; i < 4; ++i) {
            af[i][0] = *(const short8*)&Als0[(wm + i * 16 + fm) * 32 + kg * 8];
            af[i][1] = *(const short8*)&Als1[(wm + i * 16 + fm) * 32 + kg * 8];
        }
        #pragma unroll
        for (int j = 0; j < JF; ++j) {
            bfr[j][0] = *(const short8*)&Bls0[(wn + j * 16 + fm) * 32 + kg * 8];
            bfr[j][1] = *(const short8*)&Bls1[(wn + j * 16 + fm) * 32 + kg * 8];
        }
        #pragma unroll
        for (int i = 0; i < 4; ++i)
            #pragma unroll
            for (int j = 0; j < JF; ++j) {
                acc[i][j] = __builtin_amdgcn_mfma_f32_16x16x32_bf16(
                    af[i][0], bfr[j][0], acc[i][j], 0, 0, 0);
                acc[i][j] = __builtin_amdgcn_mfma_f32_16x16x32_bf16(
                    af[i][1], bfr[j][1], acc[i][j], 0, 0, 0);
            }
        __syncthreads();
    }

    const int orow0 = (lane >> 4) * 4;
    const int ocol = lane & 15;
    #pragma unroll
    for (int j2 = 0; j2 < JF; j2 += 2) {
        const int nb2 = bn + wn + j2 * 16;
        if (nb2 >= vn0) {
            // V path (transposed store) — unchanged
            #pragma unroll
            for (int jj = 0; jj < 2; ++jj) {
                const int j = j2 + jj;
                const int n = bn + wn + j * 16 + ocol;
                const float bv = bias[n];
                #pragma unroll
                for (int i = 0; i < 4; ++i) {
                    const int m0 = bm + wm + i * 16 + orow0;
                    ushort4 o;
                    o.x = f2bf(acc[i][j][0] + bv);
                    o.y = f2bf(acc[i][j][1] + bv);
                    o.z = f2bf(acc[i][j][2] + bv);
                    o.w = f2bf(acc[i][j][3] + bv);
                    *(ushort4*)&Vt[((size_t)((m0 >> 10) << 10) + (n - vn0)) * 1024 + (m0 & 1023)] = o;
                }
            }
        } else {
            // Q/K path — paired stores complete each 64B line back-to-back
            const float bv0 = bias[nb2 + ocol];
            const float bv1 = bias[nb2 + 16 + ocol];
            const bool q0s = (nb2 + ocol) < qlim;
            const bool q1s = (nb2 + 16 + ocol) < qlim;
            #pragma unroll
            for (int i = 0; i < 4; ++i) {
                const int m0 = bm + wm + i * 16 + orow0;
                #pragma unroll
                for (int r = 0; r < 4; ++r) {
                    const int m = m0 + r;
                    float v0 = acc[i][j2][r] + bv0;
                    float v1 = acc[i][j2 + 1][r] + bv1;
                    if (relu) { v0 = fmaxf(v0, 0.0f); v1 = fmaxf(v1, 0.0f); }
                    if (q0s) v0 *= 0.125f;
                    if (q1s) v1 *= 0.125f;
                    if (obf16) {
                        ((ushort*)C)[(size_t)m * N + nb2 + ocol] = f2bf(v0);
                        ((ushort*)C)[(size_t)m * N + nb2 + 16 + ocol] = f2bf(v1);
                    } else {
                        ((float*)C)[(size_t)m * N + nb2 + ocol] = v0;
                        ((float*)C)[(size_t)m * N + nb2 + 16 + ocol] = v1;
                    }
                }
            }
        }
    }
}

// ---------------- split-K bf16 MFMA GEMM, fp32 partials --------------------
// Mixed deployment (both measured): WO uses BN=128 (K=512/block — prologue-
// dominated regime where the bigger tile won); FFN2 uses BN=64 (K=2048/block
// — BN=128's occupancy drop 32->17.8% made it 53.4us vs 50.3us).
// fp32 partial stores are full 64B lines (16 lanes x 4B) — no amplification.
template<int BN>
__global__ __launch_bounds__(256)
void gemm_bf16_sk(const ushort* __restrict__ A, const ushort* __restrict__ Bt,
                  float* __restrict__ P, int M, int N, int K) {
    constexpr int JF = BN / 32;
    __shared__ ushort Als0[128 * 32];
    __shared__ ushort Als1[128 * 32];
    __shared__ ushort Bls0[BN * 32];
    __shared__ ushort Bls1[BN * 32];

    const int L = blockIdx.x + gridDim.x * blockIdx.y;
    const int xcd = L & 7;
    const int idx = L >> 3;
    const int mpx = gridDim.y >> 3;
    const int bm = (xcd * mpx + (idx % mpx)) * 128;
    const int bn = (idx / mpx) * BN;
    const int kbeg = blockIdx.z * (K >> 1);
    const int kend = kbeg + (K >> 1);

    const int t = threadIdx.x;
    const int lane = t & 63;
    const int w = t >> 6;
    const int wm = (w >> 1) * 64;
    const int wn = (w & 1) * (BN / 2);
    const int fm = lane & 15;
    const int kg = lane >> 4;

    f32x4 acc[4][JF] = {};

    for (int k0 = kbeg; k0 < kend; k0 += 64) {
        #pragma unroll
        for (int j = 0; j < 2; ++j) {
            const int chunk = j * 256 + t;
            const int row = chunk >> 2, kc = chunk & 3;
            const ushort* ga0 = A + (size_t)(bm + row) * K + k0 + kc * 8;
            __builtin_amdgcn_global_load_lds(
                (const __attribute__((address_space(1))) void*)ga0,
                (__attribute__((address_space(3))) void*)(Als0 + chunk * 8), 16, 0, 0);
            const ushort* ga1 = ga0 + 32;
            __builtin_amdgcn_global_load_lds(
                (const __attribute__((address_space(1))) void*)ga1,
                (__attribute__((address_space(3))) void*)(Als1 + chunk * 8), 16, 0, 0);
        }
        #pragma unroll
        for (int j = 0; j < BN / 64; ++j) {
            const int chunk = j * 256 + t;
            const int row = chunk >> 2, kc = chunk & 3;
            const ushort* gb0 = Bt + (size_t)(bn + row) * K + k0 + kc * 8;
            __builtin_amdgcn_global_load_lds(
                (const __attribute__((address_space(1))) void*)gb0,
                (__attribute__((address_space(3))) void*)(Bls0 + chunk * 8), 16, 0, 0);
            const ushort* gb1 = gb0 + 32;
            __builtin_amdgcn_global_load_lds(
                (const __attribute__((address_space(1))) void*)gb1,
                (__attribute__((address_space(3))) void*)(Bls1 + chunk * 8), 16, 0, 0);
        }
        __syncthreads();

        short8 af[4][2], bfr[JF][2];
        #pragma unroll
        for (int i = 0; i < 4; ++i) {
            af[i][0] = *(const short8*)&Als0[(wm + i * 16 + fm) * 32 + kg * 8];
            af[i][1] = *(const short8*)&Als1[(wm + i * 16 + fm) * 32 + kg * 8];
        }
        #pragma unroll
        for (int j = 0; j < JF; ++j) {
            bfr[j][0] = *(const short8*)&Bls0[(wn + j * 16 + fm) * 32 + kg * 8];
            bfr[j][1] = *(const short8*)&Bls1[(wn + j * 16 + fm) * 32 + kg * 8];
        }
        #pragma unroll
        for (int i = 0; i < 4; ++i)
            #pragma unroll
            for (int j = 0; j < JF; ++j) {
                acc[i][j] = __builtin_amdgcn_mfma_f32_16x16x32_bf16(
                    af[i][0], bfr[j][0], acc[i][j], 0, 0, 0);
                acc[i][j] = __builtin_amdgcn_mfma_f32_16x16x32_bf16(
                    af[i][1], bfr[j][1], acc[i][j], 0, 0, 0);
            }
        __syncthreads();
    }

    float* Pz = P + (size_t)blockIdx.z * M * N;
    const int orow0 = (lane >> 4) * 4;
    const int ocol = lane & 15;
    #pragma unroll
    for (int j = 0; j < JF; ++j) {
        const int n = bn + wn + j * 16 + ocol;
        #pragma unroll
        for (int i = 0; i < 4; ++i) {
            const int m0 = bm + wm + i * 16 + orow0;
            #pragma unroll
            for (int r = 0; r < 4; ++r)
                Pz[(size_t)(m0 + r) * N + n] = acc[i][j][r];
        }
    }
}

// ================= shared pieces for the 8-phase GEMM ======================
// Swizzle: 16B slot index (3 bits, byte-col bits 4-6) XORed with (row&7)
// within each [128 rows][64 bf16] half -> conflict-free ds_read_b128
// (verified: SQ_LDS_BANK_CONFLICT == 0 on HW). Applied both-sides (rule 21):
// linear global_load_lds dest + inverse-swizzled GLOBAL source column +
// same XOR on the ds_read address.

#define BARM() asm volatile("s_barrier" ::: "memory")
#define VMC4() asm volatile("s_waitcnt vmcnt(4)" ::: "memory")
#define LGK0() do { asm volatile("s_waitcnt lgkmcnt(0)" ::: "memory"); \
                    __builtin_amdgcn_sched_barrier(0); } while (0)

__device__ __forceinline__ short8 fragrd(const ushort* h, int row, int s, int kg) {
    const int cb = ((s << 6) + (kg << 4)) ^ ((row & 7) << 4);
    return *(const short8*)(h + row * 64 + (cb >> 1));
}

__device__ __forceinline__ void stage_half(const ushort* __restrict__ src,
                                           int srcK, ushort* ldsh, int t) {
    // src points to element (row0, kcol0) of a 128x64 half; row stride = srcK.
    #pragma unroll
    for (int l = 0; l < 2; ++l) {
        const int chunk = l * 512 + t;          // 0..1023, 16B each
        const int r = chunk >> 3;
        const int cb_log = ((chunk & 7) * 16) ^ ((r & 7) << 4);
        const ushort* g = src + (size_t)r * srcK + (cb_log >> 1);
        __builtin_amdgcn_global_load_lds(
            (const __attribute__((address_space(1))) void*)g,
            (__attribute__((address_space(3))) void*)(ldsh + chunk * 8), 16, 0, 0);
    }
}

// =================== 256x256 8-phase GEMM (T2+T3+T4+T5) ====================
// BM=BN=256, BK=64, 512 threads = 8 waves (2M x 4N), per-wave out 128x64.
// Counted vmcnt(4) at phases 4 and 8 only; never vmcnt(0) in the main loop.
// Epilogue: row-segment stores (nj innermost) — both 64B lines of each row
// segment complete back-to-back (fixes 2.5x write amplification).
// Requires: M == 4096, N%256==0, K%128==0, grid = 16*(N/256), grid%8==0.
__global__ __launch_bounds__(512, 2)
void gemm256(const ushort* __restrict__ A, const ushort* __restrict__ Bt,
             const float* __restrict__ bias, ushort* __restrict__ C,
             int M, int N, int K, int relu, int qlim) {
    __shared__ ushort lds[65536];              // 128 KiB

    const int nt = K >> 6;                     // BK=64 tiles (even)
    const int t = threadIdx.x;
    const int lane = t & 63;
    const int w = t >> 6;
    const int wr = w >> 2, wc = w & 3;
    const int fm = lane & 15, kg = lane >> 4;

    const int bid = blockIdx.x;
    const int wg = (bid & 7) * (gridDim.x >> 3) + (bid >> 3);
    const int bm = (wg & 15) << 8;
    const int bn = (wg >> 4) << 8;

    ushort* const A0 = lds;
    ushort* const B0 = lds + 16384;
    ushort* const A1 = lds + 32768;
    ushort* const B1 = lds + 49152;

    const ushort* const Ah0 = A0 + wr * 8192;
    const ushort* const Ah1 = A1 + wr * 8192;
    const ushort* const Bh0 = B0 + (wc >> 1) * 8192;
    const ushort* const Bh1 = B1 + (wc >> 1) * 8192;
    const int brow = (wc & 1) * 64;

    #define ASRC(tt, h) (A  + (size_t)(bm + (h) * 128) * K + (tt) * 64)
    #define BSRC(tt, h) (Bt + (size_t)(bn + (h) * 128) * K + (tt) * 64)

    f32x4 acc[8][4] = {};
    short8 af[4][2];
    short8 bf2[4][2];

    #define RD_A(HP, MI0) do { \
        _Pragma("unroll") \
        for (int i = 0; i < 4; ++i) { \
            const int row = ((MI0) + i) * 16 + fm; \
            af[i][0] = fragrd((HP), row, 0, kg); \
            af[i][1] = fragrd((HP), row, 1, kg); \
        } } while (0)

    #define RD_B(HP, J0) do { \
        _Pragma("unroll") \
        for (int jj = 0; jj < 2; ++jj) { \
            const int row = brow + ((J0) + jj) * 16 + fm; \
            bf2[(J0) + jj][0] = fragrd((HP), row, 0, kg); \
            bf2[(J0) + jj][1] = fragrd((HP), row, 1, kg); \
        } } while (0)

    #define QMFMA(MI0, J0) do { \
        __builtin_amdgcn_s_setprio(1); \
        _Pragma("unroll") \
        for (int i = 0; i < 4; ++i) { \
            _Pragma("unroll") \
            for (int jj = 0; jj < 2; ++jj) { \
                acc[(MI0)+i][(J0)+jj] = __builtin_amdgcn_mfma_f32_16x16x32_bf16( \
                    af[i][0], bf2[(J0)+jj][0], acc[(MI0)+i][(J0)+jj], 0, 0, 0); \
                acc[(MI0)+i][(J0)+jj] = __builtin_amdgcn_mfma_f32_16x16x32_bf16( \
                    af[i][1], bf2[(J0)+jj][1], acc[(MI0)+i][(J0)+jj], 0, 0, 0); \
            } } \
        __builtin_amdgcn_s_setprio(0); \
    } while (0)

    stage_half(BSRC(0, 0), K, B0, t);
    stage_half(BSRC(0, 1), K, B0 + 8192, t);
    stage_half(ASRC(0, 0), K, A0, t);
    stage_half(ASRC(0, 1), K, A0 + 8192, t);
    stage_half(BSRC(1, 0), K, B1, t);
    stage_half(BSRC(1, 1), K, B1 + 8192, t);
    VMC4();
    BARM();

    for (int it = 0; it < (nt >> 1); ++it) {
        const int ta = 2 * it;
        const int tb = ta + 1;
        const int t2 = min(ta + 2, nt - 1);
        const int t3 = min(ta + 3, nt - 1);

        RD_A(Ah0, 0); RD_B(Bh0, 0);
        stage_half(ASRC(tb, 0), K, A1, t);
        BARM(); LGK0(); QMFMA(0, 0); BARM();
        RD_B(Bh0, 2);
        stage_half(ASRC(tb, 1), K, A1 + 8192, t);
        BARM(); LGK0(); QMFMA(0, 2); BARM();
        RD_A(Ah0, 4);
        stage_half(BSRC(t2, 0), K, B0, t);
        BARM(); LGK0(); QMFMA(4, 2); BARM();
        stage_half(BSRC(t2, 1), K, B0 + 8192, t);
        VMC4();
        BARM(); LGK0(); QMFMA(4, 0); BARM();
        RD_A(Ah1, 0); RD_B(Bh1, 0);
        stage_half(ASRC(t2, 0), K, A0, t);
        BARM(); LGK0(); QMFMA(0, 0); BARM();
        RD_B(Bh1, 2);
        stage_half(ASRC(t2, 1), K, A0 + 8192, t);
        BARM(); LGK0(); QMFMA(0, 2); BARM();
        RD_A(Ah1, 4);
        stage_half(BSRC(t3, 0), K, B1, t);
        BARM(); LGK0(); QMFMA(4, 2); BARM();
        stage_half(BSRC(t3, 1), K, B1 + 8192, t);
        VMC4();
        BARM(); LGK0(); QMFMA(4, 0); BARM();
    }

    const int oc = lane & 15, og = lane >> 4;
    float bvv[4];
    #pragma unroll
    for (int nj = 0; nj < 4; ++nj)
        bvv[nj] = bias[bn + wc * 64 + nj * 16 + oc];
    #pragma unroll
    for (int mi = 0; mi < 8; ++mi) {
        const int m0 = bm + wr * 128 + mi * 16 + og * 4;
        #pragma unroll
        for (int r = 0; r < 4; ++r) {
            const size_t rowbase = (size_t)(m0 + r) * N;
            #pragma unroll
            for (int nj = 0; nj < 4; ++nj) {
                const int n = bn + wc * 64 + nj * 16 + oc;
                float v = acc[mi][nj][r] + bvv[nj];
                if (relu) v = fmaxf(v, 0.0f);
                if (n < qlim) v *= 0.125f;
                C[rowbase + n] = f2bf(v);
            }
        }
    }
    #undef ASRC
    #undef BSRC
    #undef RD_A
    #undef RD_B
    #undef QMFMA
}

// ---------------- MFMA flash attention, max-free softmax ----------------
__global__ __launch_bounds__(256, 4)
void attn_mfma(const ushort* __restrict__ QKVb, const ushort* __restrict__ Vt,
               const float* __restrict__ biasw, const int* __restrict__ mask,
               ushort* __restrict__ ctx) {
    const int q0 = blockIdx.x * 64;
    const int h = blockIdx.y;
    const int b = blockIdx.z;
    const int t = threadIdx.x;
    const int lane = t & 63;
    const int w = t >> 6;
    const int g = lane >> 4;
    const int c = lane & 15;

    __shared__ ushort QP[64 * 72];
    __shared__ ushort Ks[64 * 72];
    __shared__ ushort Vs[64 * 72];
    __shared__ float maskS[LL];

    #pragma unroll
    for (int i = 0; i < 2; ++i) {
        const int chunk = i * 256 + t;
        const int row = chunk >> 3, c8 = (chunk & 7) * 8;
        *(short8*)&QP[row * 72 + c8] =
            *(const short8*)(QKVb + ((size_t)(b * LL + q0 + row)) * LDQ + h * DHH + c8);
    }
    {
        int4 mi = ((const int4*)(mask + b * LL))[t];
        float4 mf;
        mf.x = mi.x ? 0.0f : -49152.0f;
        mf.y = mi.y ? 0.0f : -49152.0f;
        mf.z = mi.z ? 0.0f : -49152.0f;
        mf.w = mi.w ? 0.0f : -49152.0f;
        ((float4*)maskS)[t] = mf;
    }

    short8 pk[2], pv[2];
    #pragma unroll
    for (int i = 0; i < 2; ++i) {
        const int chunk = i * 256 + t;
        const int row = chunk >> 3, c8 = (chunk & 7) * 8;
        pk[i] = *(const short8*)(QKVb + ((size_t)(b * LL + row)) * LDQ + 1024 + h * DHH + c8);
        pv[i] = *(const short8*)(Vt + ((size_t)((b * HH + h) * DHH + row)) * LL + c8);
    }
    __syncthreads();

    short8 aq0 = *(const short8*)&QP[(w * 16 + c) * 72 + g * 8];
    short8 aq1 = *(const short8*)&QP[(w * 16 + c) * 72 + g * 8 + 32];
    ushort* Pw = QP + w * (16 * 72);

    const float* bp = biasw + (size_t)(b * LL + q0 + w * 16 + 4 * g) * 1024 + c * 4;
    float4 pb[4];
    #pragma unroll
    for (int r = 0; r < 4; ++r)
        pb[r] = *(const float4*)(bp + r * 1024);

    float l_run[4] = {0.f, 0.f, 0.f, 0.f};
    f32x4 acc_o[4] = {};

    for (int kt = 0; kt < 16; ++kt) {
        #pragma unroll
        for (int i = 0; i < 2; ++i) {
            const int chunk = i * 256 + t;
            const int row = chunk >> 3, c8 = (chunk & 7) * 8;
            *(short8*)&Ks[row * 72 + c8] = pk[i];
            *(short8*)&Vs[row * 72 + c8] = pv[i];
        }
        __syncthreads();

        if (kt < 15) {
            const int k0n = (kt + 1) * 64;
            #pragma unroll
            for (int i = 0; i < 2; ++i) {
                const int chunk = i * 256 + t;
                const int row = chunk >> 3, c8 = (chunk & 7) * 8;
                pk[i] = *(const short8*)(QKVb + ((size_t)(b * LL + k0n + row)) * LDQ + 1024 + h * DHH + c8);
                pv[i] = *(const short8*)(Vt + ((size_t)((b * HH + h) * DHH + row)) * LL + k0n + c8);
            }
        }

        float4 pbn[4];
        if (kt < 15) {
            #pragma unroll
            for (int r = 0; r < 4; ++r)
                pbn[r] = *(const float4*)(bp + r * 1024 + (kt + 1) * 64);
        }

        float mk[4];
        #pragma unroll
        for (int j = 0; j < 4; ++j) mk[j] = maskS[kt * 64 + j * 16 + c];

        f32x4 accs[4] = {};
        __builtin_amdgcn_s_setprio(1);
        #pragma unroll
        for (int j = 0; j < 4; ++j) {
            short8 bk0 = *(const short8*)&Ks[(j * 16 + c) * 72 + g * 8];
            short8 bk1 = *(const short8*)&Ks[(j * 16 + c) * 72 + g * 8 + 32];
            accs[j] = __builtin_amdgcn_mfma_f32_16x16x32_bf16(aq0, bk0, accs[j], 0, 0, 0);
            accs[j] = __builtin_amdgcn_mfma_f32_16x16x32_bf16(aq1, bk1, accs[j], 0, 0, 0);
        }
        __builtin_amdgcn_s_setprio(0);

        #pragma unroll
        for (int j = 0; j < 4; ++j)
            #pragma unroll
            for (int r = 0; r < 4; ++r) {
                const float pe = fexp2(fmaf(accs[j][r], ((const float*)&pb[r])[j], mk[j]));
                l_run[r] += pe;
                Pw[(4 * g + r) * 72 + j * 16 + c] = f2bf(pe);
            }

        __builtin_amdgcn_s_setprio(1);
        #pragma unroll
        for (int ks = 0; ks < 2; ++ks) {
            short8 ap = *(const short8*)&Pw[c * 72 + ks * 32 + g * 8];
            #pragma unroll
            for (int j = 0; j < 4; ++j) {
                short8 bv8 = *(const short8*)&Vs[(j * 16 + c) * 72 + ks * 32 + g * 8];
                acc_o[j] = __builtin_amdgcn_mfma_f32_16x16x32_bf16(ap, bv8, acc_o[j], 0, 0, 0);
            }
        }
        __builtin_amdgcn_s_setprio(0);

        if (kt < 15) {
            #pragma unroll
            for (int r = 0; r < 4; ++r) pb[r] = pbn[r];
        }
        __syncthreads();
    }

    #pragma unroll
    for (int r = 0; r < 4; ++r) {
        float l = l_run[r];
        #pragma unroll
        for (int d = 1; d < 16; d <<= 1) l += __shfl_xor(l, d);
        const float inv = 1.0f / l;
        #pragma unroll
        for (int j = 0; j < 4; ++j)
            ctx[((size_t)(b * LL + q0 + w * 16 + 4 * g + r)) * DD + h * DHH + j * 16 + c] =
                f2bf(acc_o[j][r] * inv);
    }
}

// ---------------- split-K reduce + col-bias + residual + LayerNorm ---------
// v = P0 + P1 + cb[col] + bres;  out = gamma*(v-mean)*rstd + beta  (+bf16)
// float4 everything; two-pass reduce via 64-lane shfl_xor + 4-slot LDS
// cross-wave combine (2 syncthreads total).
__global__ __launch_bounds__(256)
void add_ln_kernel(const float* __restrict__ P0, const float* __restrict__ P1,
                   const float* __restrict__ cb, const float* __restrict__ bres,
                   const float* __restrict__ gamma, const float* __restrict__ beta,
                   float* __restrict__ out, ushort* __restrict__ outb) {
    const int row = blockIdx.x;
    const int tid = threadIdx.x;
    const int lane = tid & 63;
    const int wv = tid >> 6;
    __shared__ float redS[8];

    const size_t base = (size_t)row * DD;
    const float4 p0 = ((const float4*)(P0 + base))[tid];
    const float4 p1 = ((const float4*)(P1 + base))[tid];
    const float4 br = ((const float4*)(bres + base))[tid];
    const float4 cv = ((const float4*)cb)[tid];
    float4 v;
    v.x = p0.x + p1.x + cv.x + br.x;
    v.y = p0.y + p1.y + cv.y + br.y;
    v.z = p0.z + p1.z + cv.z + br.z;
    v.w = p0.w + p1.w + cv.w + br.w;

    float s = v.x + v.y + v.z + v.w;
    #pragma unroll
    for (int d = 1; d < 64; d <<= 1) s += __shfl_xor(s, d);
    if (lane == 0) redS[wv] = s;
    __syncthreads();
    const float mean = (redS[0] + redS[1] + redS[2] + redS[3]) * (1.0f / 1024.0f);

    float4 dlt;
    dlt.x = v.x - mean; dlt.y = v.y - mean;
    dlt.z = v.z - mean; dlt.w = v.w - mean;
    float vs = dlt.x * dlt.x + dlt.y * dlt.y + dlt.z * dlt.z + dlt.w * dlt.w;
    #pragma unroll
    for (int d = 1; d < 64; d <<= 1) vs += __shfl_xor(vs, d);
    if (lane == 0) redS[4 + wv] = vs;
    __syncthreads();
    const float var = (redS[4] + redS[5] + redS[6] + redS[7]) * (1.0f / 1024.0f);
    const float rstd = rsqrtf(var + 1e-12f);

    const float4 g4 = ((const float4*)gamma)[tid];
    const float4 b4 = ((const float4*)beta)[tid];
    float4 o;
    o.x = g4.x * dlt.x * rstd + b4.x;
    o.y = g4.y * dlt.y * rstd + b4.y;
    o.z = g4.z * dlt.z * rstd + b4.z;
    o.w = g4.w * dlt.w * rstd + b4.w;
    if (out) ((float4*)(out + base))[tid] = o;
    if (outb) {
        ushort4 ob;
        ob.x = f2bf(o.x); ob.y = f2bf(o.y);
        ob.z = f2bf(o.z); ob.w = f2bf(o.w);
        ((ushort4*)(outb + base))[tid] = ob;
    }
}

extern "C" void kernel_launch(void* const* d_in, const int* in_sizes, int n_in,
                              void* d_out, int out_size, void* d_ws, size_t ws_size,
                              hipStream_t stream) {
    const float* x         = (const float*)d_in[0];
    const float* attn_bias = (const float*)d_in[1];
    const int*   src_mask  = (const int*)  d_in[2];
    const float* wq = (const float*)d_in[3];
    const float* bq = (const float*)d_in[4];
    const float* wk = (const float*)d_in[5];
    const float* bk = (const float*)d_in[6];
    const float* wv = (const float*)d_in[7];
    const float* bv = (const float*)d_in[8];
    const float* wo = (const float*)d_in[9];
    const float* bo = (const float*)d_in[10];
    const float* gamma1 = (const float*)d_in[11];
    const float* beta1  = (const float*)d_in[12];
    const float* w1 = (const float*)d_in[13];
    const float* b1 = (const float*)d_in[14];
    const float* w2 = (const float*)d_in[15];
    const float* b2 = (const float*)d_in[16];
    const float* gamma2 = (const float*)d_in[17];
    const float* beta2  = (const float*)d_in[18];
    float* out = (float*)d_out;

    // workspace arena (96 MB, time-multiplexed) — v6 layout:
    // [0,8):   xb -> ctxb (dead after WO)
    // [8,24):  QKVb(front) -> Hb fp32 (LN1 out, live till LN2)
    // [8,32):  QKVb full 24 MB (dead after attn)
    // [24,32): -> Hbb (LN1 out, FFN1 in) -> W2T (after FFN1)
    // [32,64): Vt[32,40) + WQKVT[40,46) + bqkv[46,~) + biasw[48,64)
    //          -> P_wo (WO out, LN1 in) -> F1b (FFN1 out, FFN2 in)
    // [64,72): W1T (written up-front; FFN1 in; dead)
    // [72,74): WOT (written up-front; WO in; dead)
    // [64,96): -> P_ffn2 (FFN2 out, LN2 in)
    const size_t MB = 1024 * 1024;
    char* W = (char*)d_ws;
    ushort* xb    = (ushort*)(W + 0);
    ushort* ctxb  = (ushort*)(W + 0);
    ushort* QKVb  = (ushort*)(W + 8 * MB);
    float*  Hb    = (float*) (W + 8 * MB);
    ushort* Hbb   = (ushort*)(W + 24 * MB);
    ushort* W2T   = (ushort*)(W + 24 * MB);
    ushort* Vt    = (ushort*)(W + 32 * MB);
    ushort* WQKVT = (ushort*)(W + 40 * MB);
    float*  bqkv  = (float*) (W + 46 * MB);
    float*  biasw = (float*) (W + 48 * MB);
    float*  Pwo   = (float*) (W + 32 * MB);   // 2 x 16 MB, after attn
    ushort* F1b   = (ushort*)(W + 32 * MB);   // 32 MB, after LN1
    ushort* W1T   = (ushort*)(W + 64 * MB);
    ushort* WOT   = (ushort*)(W + 72 * MB);
    float*  Pffn  = (float*) (W + 64 * MB);   // 2 x 16 MB, after FFN1

    dim3 blk(256);

    // 1. fused setup: x->xb, attn_bias->biasw, bias concat, 5 transposes
    setup_fused<<<dim3(16396), blk, 0, stream>>>(x, xb, attn_bias, biasw,
                                                 bq, bk, bv, bqkv,
                                                 wq, wk, wv, wo, w1,
                                                 WQKVT, WOT, W1T);
    // 2. fused QKV projection (bf16 out; Q scaled 0.125; V -> Vt transposed)
    gemm_bf16<128><<<dim3(24, 32), blk, 0, stream>>>(xb, WQKVT, bqkv, QKVb,
                                                     Vt, 2048, MM, LDQ, DD, 0, 1, 1024);
    // 3. MFMA flash attention -> ctx bf16
    attn_mfma<<<dim3(16, HH, BB), blk, 0, stream>>>(QKVb, Vt, biasw, src_mask, ctxb);
    // 4. split-K output projection (128x128 tiles; K=512/block — prologue-
    //    dominated regime where BN=128 measured faster). grid 8x32x2 = 512.
    gemm_bf16_sk<128><<<dim3(8, 32, 2), blk, 0, stream>>>(ctxb, WOT, Pwo, MM, DD, DD);
    // 5. h = LN(Pwo0+Pwo1+bo + x) -> Hb fp32 + Hbb bf16
    add_ln_kernel<<<dim3(MM), blk, 0, stream>>>(Pwo, Pwo + (size_t)MM * DD, bo, x,
                                                gamma1, beta1, Hb, Hbb);
    // 6. FFN1 via 256x256 8-phase kernel (relu, bias, bf16) -> F1b
    gemm256<<<dim3(256), dim3(512), 0, stream>>>(Hbb, W1T, b1, F1b,
                                                 MM, FFF, DD, 1, 0);
    // 7. W2 transpose into dead Hbb region
    transpose_cast<<<dim3(32, 128), blk, 0, stream>>>(w2, W2T, FFF, DD);
    // 8. split-K FFN2 (64-wide tiles; K=2048/block — occupancy-bound regime
    //    where BN=64's 4 blocks/CU measured faster: 50.3 vs 53.4us).
    gemm_bf16_sk<64><<<dim3(16, 32, 2), blk, 0, stream>>>(F1b, W2T, Pffn, MM, DD, FFF);
    // 9. out = LN(Pffn0+Pffn1+b2 + h)
    add_ln_kernel<<<dim3(MM), blk, 0, stream>>>(Pffn, Pffn + (size_t)MM * DD, b2, Hb,
                                                gamma2, beta2, out, nullptr);
}